// Round 4
// baseline (464.070 us; speedup 1.0000x reference)
//
#include <hip/hip_runtime.h>

// out = tanh(((LN(z) @ W + b) * scale)/3)*3
// z (16384,1024) f32, W (1024,4096) f32, out (16384,4096) f32.
// Internal: zn and Wt in bf16 for MFMA (no fp32 MFMA on CDNA4).
#define M_DIM 16384
#define K_DIM 1024
#define N_DIM 4096
#define T_TILES (K_DIM / 32)   // 32 K-tiles of BK=32

typedef __bf16 bf16x8 __attribute__((ext_vector_type(8)));
typedef float f32x16 __attribute__((ext_vector_type(16)));

__device__ __forceinline__ unsigned short f2bf(float f) {
    union { float f; unsigned int i; } v; v.f = f;
    unsigned int r = v.i + 0x7fffu + ((v.i >> 16) & 1u);  // round-to-nearest-even
    return (unsigned short)(r >> 16);
}
__device__ __forceinline__ unsigned int pack2(float lo, float hi) {
    return ((unsigned int)f2bf(lo)) | (((unsigned int)f2bf(hi)) << 16);
}

// ---------------- Fused prep: LN (blocks [0,4096)) + W transpose (blocks [4096,8192)) ----------------
// LN: one wave per row of 1024, fp32 in -> bf16 out. Fully coalesced.
// TR: 32x32 tile transpose+convert of W (K,N) -> Wt (N,K).
__global__ __launch_bounds__(256) void prep_kernel(
        const float* __restrict__ z,
        const float* __restrict__ gamma,
        const float* __restrict__ beta,
        unsigned short* __restrict__ zn,
        const float* __restrict__ W,
        unsigned short* __restrict__ Wt) {
    __shared__ float t[32][33];
    const int tid = threadIdx.x;
    if (blockIdx.x < M_DIM / 4) {
        const int wave = tid >> 6;
        const int lane = tid & 63;
        const size_t row = (size_t)blockIdx.x * 4 + wave;
        const float* zr = z + row * K_DIM;

        float4 x[4];
#pragma unroll
        for (int v = 0; v < 4; v++) x[v] = *(const float4*)(zr + v * 256 + lane * 4);

        float s = 0.f, ss = 0.f;
#pragma unroll
        for (int v = 0; v < 4; v++) {
            s  += x[v].x + x[v].y + x[v].z + x[v].w;
            ss += x[v].x * x[v].x + x[v].y * x[v].y + x[v].z * x[v].z + x[v].w * x[v].w;
        }
#pragma unroll
        for (int o = 32; o; o >>= 1) { s += __shfl_xor(s, o, 64); ss += __shfl_xor(ss, o, 64); }
        const float mean = s * (1.f / K_DIM);
        const float var = ss * (1.f / K_DIM) - mean * mean;
        const float rstd = rsqrtf(var + 1e-5f);

#pragma unroll
        for (int v = 0; v < 4; v++) {
            float4 g = *(const float4*)(gamma + v * 256 + lane * 4);
            float4 b = *(const float4*)(beta + v * 256 + lane * 4);
            float o0 = (x[v].x - mean) * rstd * g.x + b.x;
            float o1 = (x[v].y - mean) * rstd * g.y + b.y;
            float o2 = (x[v].z - mean) * rstd * g.z + b.z;
            float o3 = (x[v].w - mean) * rstd * g.w + b.w;
            uint2 q; q.x = pack2(o0, o1); q.y = pack2(o2, o3);
            *(uint2*)(zn + row * K_DIM + v * 256 + lane * 4) = q;
        }
    } else {
        const int bid = blockIdx.x - M_DIM / 4;
        const int tx = tid & 31, ty = tid >> 5;           // (32, 8)
        const int n0 = (bid & (N_DIM / 32 - 1)) * 32, k0 = (bid / (N_DIM / 32)) * 32;
#pragma unroll
        for (int j = 0; j < 32; j += 8)
            t[ty + j][tx] = W[(size_t)(k0 + ty + j) * N_DIM + n0 + tx];
        __syncthreads();
#pragma unroll
        for (int j = 0; j < 32; j += 8)
            Wt[(size_t)(n0 + ty + j) * K_DIM + k0 + tx] = f2bf(t[tx][ty + j]);
    }
}

// ---------------- GEMM: 256x256 tile, 8 waves, ring-4 LDS, counted-vmcnt pipeline ----------------
// zn (M,K)bf16 @ Wt (N,K)bf16 with 32x32x16 MFMA.
// LDS layout per 256x32 tile (A or B): 16B-unit index of (row, chunk c in [0,4)) is
//   u = row*4 + (c ^ ((row>>1)&3))
// global_load_lds writes lane l's 16B at base + l*16, so the staging source for unit u
// fetches row (u>>2), chunk ((u&3) ^ ((u>>3)&3)).
// Schedule (m201-style issue->barrier->consume): per K-tile t
//   [frags a(rows 0..63), b pre-issued at end of tile t-1]
//   STAGE_A(t+3) ; barrier ; lgkmcnt(0) ; 8 MFMA (acc[0..1][*])
//   read a(rows 64..127) ; STAGE_B(t+3) ; barrier ; lgkmcnt(0) ; 8 MFMA (acc[2..3][*])
//   vmcnt(8) ; barrier ; issue frags for tile t+1
// vmcnt(8) keeps 2 tiles (8 loads) in flight across barriers; never drains to 0 mid-loop.
__device__ __forceinline__ void async_copy16(const unsigned short* g, unsigned short* l) {
    __builtin_amdgcn_global_load_lds(
        (const __attribute__((address_space(1))) unsigned int*)g,
        (__attribute__((address_space(3))) unsigned int*)l,
        16, 0, 0);
}

__global__ __launch_bounds__(512, 2) void gemm_kernel(
        const unsigned short* __restrict__ A,   // zn, (M, K) bf16
        const unsigned short* __restrict__ B,   // Wt, (N, K) bf16
        const float* __restrict__ bias,
        const float* __restrict__ scale,
        float* __restrict__ out) {
    __shared__ __align__(16) unsigned short As[4][256 * 32];   // 4 x 16 KB
    __shared__ __align__(16) unsigned short Bs[4][256 * 32];   // 4 x 16 KB  (total 128 KB)

    const int tid = threadIdx.x;
    const int wave = tid >> 6, lane = tid & 63;
    const int wm = wave >> 2, wn = wave & 3;     // 2x4 wave grid, each 128x64 of the 256x256 tile
    const int l31 = lane & 31, lhi = lane >> 5;

    // T1: XCD-aware block swizzle. nwg = 16*64 = 1024, divisible by 8.
    const int bid = blockIdx.y * gridDim.x + blockIdx.x;
    const int id2 = (bid & 7) * 128 + (bid >> 3);
    const int bm = id2 >> 4, bn = id2 & 15;      // bm in [0,64), bn in [0,16)

    // Staging source: thread tid covers unit u = q*512 + tid of each 256x32 tile.
    const int r0 = tid >> 2;
    const int c0 = ((tid & 3) ^ ((tid >> 3) & 3)) << 3;        // bf16 elem offset of swizzled chunk
    const unsigned short* agA = A + (size_t)(bm * 256 + r0) * K_DIM + c0;
    const unsigned short* agB = B + (size_t)(bn * 256 + r0) * K_DIM + c0;
    const int ldsu = wave * 512;   // elem offset of this wave's 64x16B chunk (q=0)

#define STAGE_A(t_, s_) do { \
        const unsigned short* g_ = agA + (t_) * 32; \
        async_copy16(g_,                 &As[s_][ldsu]); \
        async_copy16(g_ + 128 * K_DIM,   &As[s_][4096 + ldsu]); } while (0)
#define STAGE_B(t_, s_) do { \
        const unsigned short* g_ = agB + (t_) * 32; \
        async_copy16(g_,                 &Bs[s_][ldsu]); \
        async_copy16(g_ + 128 * K_DIM,   &Bs[s_][4096 + ldsu]); } while (0)

    f32x16 acc[4][2] = {};
    const int swz = (l31 >> 1) & 3;   // row-dependent XOR for fragment reads (row base % 32 == 0)
    bf16x8 a[2][2], b[2][2];

    // Frag-read helpers (slot pointer, a-row base within wave's 128)
#define READ_A(s_, rb_) do { \
        const unsigned short* as_ = As[s_]; \
        _Pragma("unroll") \
        for (int i_ = 0; i_ < 2; ++i_) \
        _Pragma("unroll") \
        for (int ks_ = 0; ks_ < 2; ++ks_) \
            a[i_][ks_] = *(const bf16x8*)&as_[(wm * 128 + (rb_) + i_ * 32 + l31) * 32 + (((2 * ks_ + lhi) ^ swz) << 3)]; } while (0)
#define READ_B(s_) do { \
        const unsigned short* bs_ = Bs[s_]; \
        _Pragma("unroll") \
        for (int j_ = 0; j_ < 2; ++j_) \
        _Pragma("unroll") \
        for (int ks_ = 0; ks_ < 2; ++ks_) \
            b[j_][ks_] = *(const bf16x8*)&bs_[(wn * 64 + j_ * 32 + l31) * 32 + (((2 * ks_ + lhi) ^ swz) << 3)]; } while (0)

    // Prologue: prefetch K-tiles 0,1,2 (12 loads in flight).
    STAGE_A(0, 0); STAGE_B(0, 0);
    STAGE_A(1, 1); STAGE_B(1, 1);
    STAGE_A(2, 2); STAGE_B(2, 2);
    asm volatile("s_waitcnt vmcnt(8)" ::: "memory");   // tile 0's 4 loads retired
    __builtin_amdgcn_s_barrier();
    asm volatile("" ::: "memory");
    READ_A(0, 0); READ_B(0);                           // issue tile-0 frags (consumed after next barrier)

#pragma unroll 4
    for (int t = 0; t < T_TILES; ++t) {
        const int s = t & 3, sn = (t + 1) & 3, ss = (t + 3) & 3;

        if (t + 3 < T_TILES) STAGE_A(t + 3, ss);       // writes slot (t-1)&3: all its readers done
        asm volatile("" ::: "memory");
        __builtin_amdgcn_s_barrier();
        asm volatile("s_waitcnt lgkmcnt(0)" ::: "memory");
        __builtin_amdgcn_sched_barrier(0);
        __builtin_amdgcn_s_setprio(1);
#pragma unroll
        for (int ks = 0; ks < 2; ++ks)
#pragma unroll
            for (int i = 0; i < 2; ++i)
#pragma unroll
                for (int j = 0; j < 2; ++j)
                    acc[i][j] = __builtin_amdgcn_mfma_f32_32x32x16_bf16(a[i][ks], b[j][ks], acc[i][j], 0, 0, 0);
        __builtin_amdgcn_s_setprio(0);

        READ_A(s, 64);                                 // rows [64,128) of wave tile, same slot
        if (t + 3 < T_TILES) STAGE_B(t + 3, ss);
        asm volatile("" ::: "memory");
        __builtin_amdgcn_s_barrier();
        asm volatile("s_waitcnt lgkmcnt(0)" ::: "memory");
        __builtin_amdgcn_sched_barrier(0);
        __builtin_amdgcn_s_setprio(1);
#pragma unroll
        for (int ks = 0; ks < 2; ++ks)
#pragma unroll
            for (int i = 0; i < 2; ++i)
#pragma unroll
                for (int j = 0; j < 2; ++j)
                    acc[2 + i][j] = __builtin_amdgcn_mfma_f32_32x32x16_bf16(a[i][ks], b[j][ks], acc[2 + i][j], 0, 0, 0);
        __builtin_amdgcn_s_setprio(0);

        if (t < T_TILES - 1) {
            // Counted wait for tile t+1's data; keep later tiles' loads in flight.
            if (t < T_TILES - 3)       asm volatile("s_waitcnt vmcnt(8)" ::: "memory");
            else if (t == T_TILES - 3) asm volatile("s_waitcnt vmcnt(4)" ::: "memory");
            else                       asm volatile("s_waitcnt vmcnt(0)" ::: "memory");
            __builtin_amdgcn_s_barrier();
            asm volatile("" ::: "memory");
            READ_A(sn, 0); READ_B(sn);                 // issue next tile's frags
        }
    }
#undef STAGE_A
#undef STAGE_B
#undef READ_A
#undef READ_B

    // Epilogue: out = 3*tanh(x/3) = 3 - 6/(exp2(x*2/(3 ln2)) + 1); saturates correctly at +-inf.
    const float mfac = scale[0] * 0.96179669392236f;   // scale * 2/(3*ln2)
#pragma unroll
    for (int j = 0; j < 2; ++j) {
        const int gcol = bn * 256 + wn * 64 + j * 32 + l31;
        const float bv = bias[gcol];
#pragma unroll
        for (int i = 0; i < 4; ++i) {
            const int rbase = bm * 256 + wm * 128 + i * 32 + 4 * lhi;
#pragma unroll
            for (int r = 0; r < 16; ++r) {
                const int grow = rbase + (r & 3) + 8 * (r >> 2);
                float tv = (acc[i][j][r] + bv) * mfac;
                float e = __builtin_amdgcn_exp2f(tv);
                out[(size_t)grow * N_DIM + gcol] = 3.f - 6.f * __builtin_amdgcn_rcpf(e + 1.f);
            }
        }
    }
}

extern "C" void kernel_launch(void* const* d_in, const int* in_sizes, int n_in,
                              void* d_out, int out_size, void* d_ws, size_t ws_size,
                              hipStream_t stream) {
    const float* z     = (const float*)d_in[0];
    const float* gamma = (const float*)d_in[1];
    const float* beta  = (const float*)d_in[2];
    const float* W     = (const float*)d_in[3];
    const float* b     = (const float*)d_in[4];
    const float* scale = (const float*)d_in[5];
    float* out = (float*)d_out;

    unsigned short* zn = (unsigned short*)d_ws;                 // 16384*1024 bf16 = 32 MB
    unsigned short* Wt = zn + (size_t)M_DIM * K_DIM;            // 4096*1024 bf16  =  8 MB

    prep_kernel<<<M_DIM / 4 + (N_DIM / 32) * (K_DIM / 32), 256, 0, stream>>>(z, gamma, beta, zn, W, Wt);
    gemm_kernel<<<dim3(N_DIM / 256, M_DIM / 256), 512, 0, stream>>>(zn, Wt, b, scale, out);
}

// Round 7
// 463.158 us; speedup vs baseline: 1.0020x; 1.0020x over previous
//
#include <hip/hip_runtime.h>

// out = tanh(((LN(z) @ W + b) * scale)/3)*3
// z (16384,1024) f32, W (1024,4096) f32, out (16384,4096) f32.
// Internal: zn and Wt in bf16 for MFMA (no fp32 MFMA on CDNA4).
#define M_DIM 16384
#define K_DIM 1024
#define N_DIM 4096
#define T_TILES (K_DIM / 64)   // 16 K-tiles of BK=64

typedef __bf16 bf16x8 __attribute__((ext_vector_type(8)));
typedef float f32x16 __attribute__((ext_vector_type(16)));

__device__ __forceinline__ unsigned short f2bf(float f) {
    union { float f; unsigned int i; } v; v.f = f;
    unsigned int r = v.i + 0x7fffu + ((v.i >> 16) & 1u);  // round-to-nearest-even
    return (unsigned short)(r >> 16);
}
__device__ __forceinline__ unsigned int pack2(float lo, float hi) {
    return ((unsigned int)f2bf(lo)) | (((unsigned int)f2bf(hi)) << 16);
}

// ---------------- Fused prep: LN (blocks [0,4096)) + W transpose (blocks [4096,8192)) ----------------
__global__ __launch_bounds__(256) void prep_kernel(
        const float* __restrict__ z,
        const float* __restrict__ gamma,
        const float* __restrict__ beta,
        unsigned short* __restrict__ zn,
        const float* __restrict__ W,
        unsigned short* __restrict__ Wt) {
    __shared__ float t[32][33];
    const int tid = threadIdx.x;
    if (blockIdx.x < M_DIM / 4) {
        const int wave = tid >> 6;
        const int lane = tid & 63;
        const size_t row = (size_t)blockIdx.x * 4 + wave;
        const float* zr = z + row * K_DIM;

        float4 x[4];
#pragma unroll
        for (int v = 0; v < 4; v++) x[v] = *(const float4*)(zr + v * 256 + lane * 4);

        float s = 0.f, ss = 0.f;
#pragma unroll
        for (int v = 0; v < 4; v++) {
            s  += x[v].x + x[v].y + x[v].z + x[v].w;
            ss += x[v].x * x[v].x + x[v].y * x[v].y + x[v].z * x[v].z + x[v].w * x[v].w;
        }
#pragma unroll
        for (int o = 32; o; o >>= 1) { s += __shfl_xor(s, o, 64); ss += __shfl_xor(ss, o, 64); }
        const float mean = s * (1.f / K_DIM);
        const float var = ss * (1.f / K_DIM) - mean * mean;
        const float rstd = rsqrtf(var + 1e-5f);

#pragma unroll
        for (int v = 0; v < 4; v++) {
            float4 g = *(const float4*)(gamma + v * 256 + lane * 4);
            float4 b = *(const float4*)(beta + v * 256 + lane * 4);
            float o0 = (x[v].x - mean) * rstd * g.x + b.x;
            float o1 = (x[v].y - mean) * rstd * g.y + b.y;
            float o2 = (x[v].z - mean) * rstd * g.z + b.z;
            float o3 = (x[v].w - mean) * rstd * g.w + b.w;
            uint2 q; q.x = pack2(o0, o1); q.y = pack2(o2, o3);
            *(uint2*)(zn + row * K_DIM + v * 256 + lane * 4) = q;
        }
    } else {
        const int bid = blockIdx.x - M_DIM / 4;
        const int tx = tid & 31, ty = tid >> 5;           // (32, 8)
        const int n0 = (bid & (N_DIM / 32 - 1)) * 32, k0 = (bid / (N_DIM / 32)) * 32;
#pragma unroll
        for (int j = 0; j < 32; j += 8)
            t[ty + j][tx] = W[(size_t)(k0 + ty + j) * N_DIM + n0 + tx];
        __syncthreads();
#pragma unroll
        for (int j = 0; j < 32; j += 8)
            Wt[(size_t)(n0 + ty + j) * K_DIM + k0 + tx] = f2bf(t[tx][ty + j]);
    }
}

// ---------------- GEMM: 256x256 tile, 8 waves, BK=64 (128-B rows), dbuf, counted vmcnt ----------------
// LDS tile (A or B): 256 rows x 64 bf16 (128 B rows -> row drops out of bank index).
// 16B-unit index of (row, chunk c in [0,8)):  u = row*8 + (c ^ (row&7))
//   -> the m214-verified "byte ^= (row&7)<<4" anti-conflict swizzle: a frag read of
//      32 consecutive rows at fixed c spreads across all 8 16B slots (4 lanes/slot).
// global_load_lds writes linearly (unit = 512p + tid), so staging thread tid fetches
//   row = (tid>>3)+64p, c = (tid&7) ^ ((tid>>3)&7)   (same involution on the source side).
// Pipeline: double-buffer, STAGE(t+2) issued before vmcnt(8) so 8 loads stay in flight.
__device__ __forceinline__ void async_copy16(const unsigned short* g, unsigned short* l) {
    __builtin_amdgcn_global_load_lds(
        (const __attribute__((address_space(1))) unsigned int*)g,
        (__attribute__((address_space(3))) unsigned int*)l,
        16, 0, 0);
}

__global__ __launch_bounds__(512, 2) void gemm_kernel(
        const unsigned short* __restrict__ A,   // zn, (M, K) bf16
        const unsigned short* __restrict__ B,   // Wt, (N, K) bf16
        const float* __restrict__ bias,
        const float* __restrict__ scale,
        float* __restrict__ out) {
    __shared__ __align__(16) unsigned short As[2][256 * 64];   // 2 x 32 KB
    __shared__ __align__(16) unsigned short Bs[2][256 * 64];   // 2 x 32 KB  (total 128 KB)

    const int tid = threadIdx.x;
    const int wave = tid >> 6, lane = tid & 63;
    const int wm = wave >> 2, wn = wave & 3;     // 2x4 wave grid, each 128x64 of the 256x256 tile
    const int l31 = lane & 31, lhi = lane >> 5;

    // T1: XCD-aware block swizzle. nwg = 16*64 = 1024, divisible by 8.
    const int bid = blockIdx.y * gridDim.x + blockIdx.x;
    const int id2 = (bid & 7) * 128 + (bid >> 3);
    const int bm = id2 >> 4, bn = id2 & 15;      // bm in [0,64), bn in [0,16)

    // Staging source (per 256x64 tile): thread tid covers units {512p + tid}, p=0..3.
    const int r0 = tid >> 3;                                   // row (+64p)
    const int c0 = ((tid & 7) ^ ((tid >> 3) & 7)) << 3;        // swizzled chunk, bf16 elems
    const unsigned short* agA = A + (size_t)(bm * 256 + r0) * K_DIM + c0;
    const unsigned short* agB = B + (size_t)(bn * 256 + r0) * K_DIM + c0;
    const int ldsu = wave * 512;   // elem offset of this wave's 64x16B chunk (p=0)

#define STAGE(t_, s_) do { \
        const unsigned short* gA_ = agA + (t_) * 64; \
        const unsigned short* gB_ = agB + (t_) * 64; \
        async_copy16(gA_,                 &As[s_][ldsu]); \
        async_copy16(gA_ +  64 * K_DIM,   &As[s_][ldsu + 4096]); \
        async_copy16(gA_ + 128 * K_DIM,   &As[s_][ldsu + 8192]); \
        async_copy16(gA_ + 192 * K_DIM,   &As[s_][ldsu + 12288]); \
        async_copy16(gB_,                 &Bs[s_][ldsu]); \
        async_copy16(gB_ +  64 * K_DIM,   &Bs[s_][ldsu + 4096]); \
        async_copy16(gB_ + 128 * K_DIM,   &Bs[s_][ldsu + 8192]); \
        async_copy16(gB_ + 192 * K_DIM,   &Bs[s_][ldsu + 12288]); } while (0)

    f32x16 acc[4][2] = {};
    bf16x8 a[2][4], b[2][4];
    const int rsw = l31 & 7;       // (row & 7) for frag rows (row base is a multiple of 32)

    // Frag reads: (row, c) lives at elem row*64 + ((c ^ (row&7)) << 3).
#define READ_A(s_, h_) do { \
        const unsigned short* as_ = As[s_]; \
        _Pragma("unroll") \
        for (int i_ = 0; i_ < 2; ++i_) \
        _Pragma("unroll") \
        for (int ks_ = 0; ks_ < 4; ++ks_) \
            a[i_][ks_] = *(const bf16x8*)&as_[(wm * 128 + (h_) * 64 + i_ * 32 + l31) * 64 + (((2 * ks_ + lhi) ^ rsw) << 3)]; } while (0)
#define READ_B(s_) do { \
        const unsigned short* bs_ = Bs[s_]; \
        _Pragma("unroll") \
        for (int j_ = 0; j_ < 2; ++j_) \
        _Pragma("unroll") \
        for (int ks_ = 0; ks_ < 4; ++ks_) \
            b[j_][ks_] = *(const bf16x8*)&bs_[(wn * 64 + j_ * 32 + l31) * 64 + (((2 * ks_ + lhi) ^ rsw) << 3)]; } while (0)

    // Prologue: stage tiles 0 and 1 (16 loads); wait for tile 0 (retire oldest 8).
    STAGE(0, 0);
    STAGE(1, 1);
    asm volatile("s_waitcnt vmcnt(8)" ::: "memory");
    __builtin_amdgcn_s_barrier();
    asm volatile("" ::: "memory");

#pragma unroll 2
    for (int t = 0; t < T_TILES; ++t) {
        const int s = t & 1;

        READ_B(s);
        READ_A(s, 0);
        asm volatile("s_waitcnt lgkmcnt(0)" ::: "memory");
        __builtin_amdgcn_sched_barrier(0);
        __builtin_amdgcn_s_setprio(1);
#pragma unroll
        for (int ks = 0; ks < 4; ++ks)
#pragma unroll
            for (int i = 0; i < 2; ++i)
#pragma unroll
                for (int j = 0; j < 2; ++j)
                    acc[i][j] = __builtin_amdgcn_mfma_f32_32x32x16_bf16(a[i][ks], b[j][ks], acc[i][j], 0, 0, 0);
        __builtin_amdgcn_s_setprio(0);

        READ_A(s, 1);
        asm volatile("s_waitcnt lgkmcnt(0)" ::: "memory");
        __builtin_amdgcn_sched_barrier(0);
        __builtin_amdgcn_s_setprio(1);
#pragma unroll
        for (int ks = 0; ks < 4; ++ks)
#pragma unroll
            for (int i = 0; i < 2; ++i)
#pragma unroll
                for (int j = 0; j < 2; ++j)
                    acc[2 + i][j] = __builtin_amdgcn_mfma_f32_32x32x16_bf16(a[i][ks], b[j][ks], acc[2 + i][j], 0, 0, 0);
        __builtin_amdgcn_s_setprio(0);

        if (t < T_TILES - 1) {
            // All this wave's reads of buf s are drained (lgkmcnt(0) above); join, then overwrite.
            __builtin_amdgcn_s_barrier();
            asm volatile("" ::: "memory");
            if (t + 2 < T_TILES) {
                STAGE(t + 2, s);
                asm volatile("s_waitcnt vmcnt(8)" ::: "memory");   // retire tile t+1's 8 loads
            } else {
                asm volatile("s_waitcnt vmcnt(0)" ::: "memory");   // tail: only t+1 outstanding
            }
            __builtin_amdgcn_s_barrier();
            asm volatile("" ::: "memory");
        }
    }
#undef STAGE
#undef READ_A
#undef READ_B

    // Epilogue: out = 3*tanh(x/3) = 3 - 6/(exp2(x*2/(3 ln2)) + 1); saturates correctly at +-inf.
    const float mfac = scale[0] * 0.96179669392236f;   // scale * 2/(3*ln2)
#pragma unroll
    for (int j = 0; j < 2; ++j) {
        const int gcol = bn * 256 + wn * 64 + j * 32 + l31;
        const float bv = bias[gcol];
#pragma unroll
        for (int i = 0; i < 4; ++i) {
            const int rbase = bm * 256 + wm * 128 + i * 32 + 4 * lhi;
#pragma unroll
            for (int r = 0; r < 16; ++r) {
                const int grow = rbase + (r & 3) + 8 * (r >> 2);
                float tv = (acc[i][j][r] + bv) * mfac;
                float e = __builtin_amdgcn_exp2f(tv);
                out[(size_t)grow * N_DIM + gcol] = 3.f - 6.f * __builtin_amdgcn_rcpf(e + 1.f);
            }
        }
    }
}

extern "C" void kernel_launch(void* const* d_in, const int* in_sizes, int n_in,
                              void* d_out, int out_size, void* d_ws, size_t ws_size,
                              hipStream_t stream) {
    const float* z     = (const float*)d_in[0];
    const float* gamma = (const float*)d_in[1];
    const float* beta  = (const float*)d_in[2];
    const float* W     = (const float*)d_in[3];
    const float* b     = (const float*)d_in[4];
    const float* scale = (const float*)d_in[5];
    float* out = (float*)d_out;

    unsigned short* zn = (unsigned short*)d_ws;                 // 16384*1024 bf16 = 32 MB
    unsigned short* Wt = zn + (size_t)M_DIM * K_DIM;            // 4096*1024 bf16  =  8 MB

    prep_kernel<<<M_DIM / 4 + (N_DIM / 32) * (K_DIM / 32), 256, 0, stream>>>(z, gamma, beta, zn, W, Wt);
    gemm_kernel<<<dim3(N_DIM / 256, M_DIM / 256), 512, 0, stream>>>(zn, Wt, b, scale, out);
}